// Round 1
// 749.948 us; speedup vs baseline: 1.0919x; 1.0919x over previous
//
#include <hip/hip_runtime.h>
#include <cstdint>
#include <cstddef>

#define NUM_NODES 200000
#define NODE_DIM  256
#define MSG_DIM   685
#define NUM_UPD   65536
#define KPAD      960     // [msg 685 | pad 3 | h 256 at col 688 | pad 16]
#define H_OFF     688
#define H_END     944
#define NOUT      1024    // 256 dims * 4 gates, interleaved per 16-col tile
#define NT        (KPAD / 64)   // 15 K-tiles

typedef __bf16 bf16;
typedef bf16  bf16x8 __attribute__((ext_vector_type(8)));
typedef float f32x4  __attribute__((ext_vector_type(4)));
typedef int   i32x4  __attribute__((ext_vector_type(4)));

__device__ __forceinline__ void async_load16(const void* g, void* l) {
    __builtin_amdgcn_global_load_lds(
        (const __attribute__((address_space(1))) void*)g,
        (__attribute__((address_space(3))) void*)l,
        16, 0, 0);
}

__device__ __forceinline__ uint32_t lds_off(const void* p) {
    return (uint32_t)(uintptr_t)(__attribute__((address_space(3))) const void*)p;
}

__device__ __forceinline__ bf16x8 dsr128(uint32_t addr) {
    i32x4 r;
    asm volatile("ds_read_b128 %0, %1" : "=v"(r) : "v"(addr));
    return __builtin_bit_cast(bf16x8, r);
}

__device__ __forceinline__ unsigned short f2bf(float v) {
    return __builtin_bit_cast(unsigned short, (bf16)v);
}

__device__ inline float sigmoidf_(float x) { return 1.0f / (1.0f + __expf(-x)); }
__device__ inline float tanhf_(float x)    { return 1.0f - 2.0f / (1.0f + __expf(2.0f * x)); }

#define BAR  __builtin_amdgcn_s_barrier()
#define LGKM0 do { asm volatile("s_waitcnt lgkmcnt(0)" ::: "memory"); \
                   __builtin_amdgcn_sched_barrier(0); } while (0)
#define VMW(n) asm volatile("s_waitcnt vmcnt(" #n ")" ::: "memory")

// ---- last-write-wins resolution ---------------------------------------------
__global__ void k_winner(const int* __restrict__ idx, int* __restrict__ winner) {
    int u = blockIdx.x * 256 + threadIdx.x;
    atomicMax(&winner[idx[u]], u);
}

// ---- copy-through of untouched rows (grid-stride) ---------------------------
__global__ void k_copy(const float* __restrict__ mem, const int* __restrict__ winner,
                       float* __restrict__ out) {
    int wv = threadIdx.x >> 6;
    int c  = threadIdx.x & 63;                        // 64 float4 per row
    for (int row = blockIdx.x * 4 + wv; row < NUM_NODES; row += 2048 * 4) {
        if (winner[row] >= 0) continue;               // epilogue will write it
        const float4* src = (const float4*)(mem + (size_t)row * NODE_DIM);
        float4*       dst = (float4*)(out + (size_t)row * NODE_DIM);
        dst[c] = src[c];
    }
}

// ---- build gate-interleaved combined weight Wc [NOUT x KPAD] (B^T layout) ----
// out col n: ntile=n>>4, gate=ntile&3, dim=(ntile>>2)*16 + (n&15)
// k < 685          : msg part (W_ih rows gate*256+dim; gate 3 -> 0)
// 688 <= k < 944   : h part   (W_hh rows for gates 0,1; gate3=n_h; gate2 -> 0)
__global__ void k_prep_wc(const float* __restrict__ W_ih, const float* __restrict__ W_hh,
                          bf16* __restrict__ Wc) {
    int n = blockIdx.x;
    int ntile = n >> 4, cc = n & 15;
    int gate = ntile & 3;
    int dim  = (ntile >> 2) * 16 + cc;
    for (int i = 0; i < 4; i++) {
        int k = i * 256 + (int)threadIdx.x;
        if (k >= KPAD) break;
        float v = 0.f;
        if (k < MSG_DIM) {
            if (gate == 0)      v = W_ih[(size_t)dim * MSG_DIM + k];
            else if (gate == 1) v = W_ih[(size_t)(256 + dim) * MSG_DIM + k];
            else if (gate == 2) v = W_ih[(size_t)(512 + dim) * MSG_DIM + k];
        } else if (k >= H_OFF && k < H_END) {
            int j = k - H_OFF;
            if (gate == 0)      v = W_hh[(size_t)dim * NODE_DIM + j];
            else if (gate == 1) v = W_hh[(size_t)(256 + dim) * NODE_DIM + j];
            else if (gate == 3) v = W_hh[(size_t)(512 + dim) * NODE_DIM + j];
        }
        Wc[(size_t)n * KPAD + k] = (bf16)v;
    }
}

// ---- build X = [messages | pad | gathered h | pad] in bf16 [NUM_UPD x KPAD] --
__global__ void k_prep_x(const float* __restrict__ msgs, const float* __restrict__ mem,
                         const int* __restrict__ idx, bf16* __restrict__ X) {
    int u = blockIdx.x;
    int t = threadIdx.x;                  // 448 threads
    bf16* xrow = X + (size_t)u * KPAD;
    if (t < 344) {                        // cols 0..687 as ushort2
        const float* mrow = msgs + (size_t)u * MSG_DIM;
        int c0 = 2 * t;
        float v0 = (c0     < MSG_DIM) ? mrow[c0]     : 0.f;
        float v1 = (c0 + 1 < MSG_DIM) ? mrow[c0 + 1] : 0.f;
        ushort2 p; p.x = f2bf(v0); p.y = f2bf(v1);
        ((ushort2*)xrow)[t] = p;
    } else if (t < 408) {                 // h: 64 threads x float4 -> ushort4
        int j = t - 344;
        const float4* h4p = (const float4*)(mem + (size_t)idx[u] * NODE_DIM);
        float4 h4 = h4p[j];
        ushort4 p; p.x = f2bf(h4.x); p.y = f2bf(h4.y); p.z = f2bf(h4.z); p.w = f2bf(h4.w);
        ((ushort4*)(xrow + H_OFF))[j] = p;
    } else if (t < 412) {                 // trailing pad cols 944..959
        int j = t - 408;
        ushort4 z; z.x = z.y = z.z = z.w = 0;
        ((ushort4*)(xrow + H_END))[j] = z;
    }
}

// ---- fused GEMM (X * Wc^T) + GRU epilogue + guarded scatter ------------------
// BM=BN=256 BK=64, 8 waves (2Mx4N), 4-phase/K-tile schedule, counted vmcnt,
// XOR-swizzled LDS (write side: pre-swizzled global src; read side: addr XOR).
__global__ __launch_bounds__(512, 2) void k_gemm(
        const bf16* __restrict__ X, const bf16* __restrict__ Wc,
        const float* __restrict__ mem, const int* __restrict__ idx,
        const int* __restrict__ winner,
        const float* __restrict__ b_ih, const float* __restrict__ b_hh,
        float* __restrict__ out) {
    // [buf0: A 16K | B 16K][buf1: A 16K | B 16K] bf16 elems = 128 KiB
    __shared__ __align__(128) bf16 lds[2 * 2 * 16384];

    const int tid = threadIdx.x;
    const int w  = tid >> 6, l = tid & 63;
    const int wr = w >> 2,  wc = w & 3;          // 2M x 4N waves
    const int quad = l >> 4, c = l & 15;

    // XCD-aware bijective swizzle: 1024 blocks, 1024 % 8 == 0
    const int bid = blockIdx.x;
    const int wg  = (bid & 7) * 128 + (bid >> 3);
    const int bm  = wg >> 2;                     // 256 m-blocks
    const int bn  = wg & 3;                      // 4 n-blocks (share A panel)

    f32x4 acc[8][4];
    #pragma unroll
    for (int i = 0; i < 8; i++)
        #pragma unroll
        for (int j = 0; j < 4; j++) acc[i][j] = (f32x4){0.f, 0.f, 0.f, 0.f};

    // ---- staging geometry: chunk = 64 rows x 64 cols = 8KB = 512 lanes x 16B
    // write side is linear; the SOURCE column-group is pre-swizzled so that the
    // read-side address XOR ((row&7)<<4) sees correct data (rule #21).
    const int srow  = tid >> 3;                          // row within chunk
    const int scol8 = (((tid & 7) ^ (srow & 7)) << 3);   // swizzled col (elems)
    const bf16* gAt = X  + ((size_t)(bm * 256) + srow) * KPAD + scol8;
    const bf16* gBt = Wc + ((size_t)(bn * 256) + srow) * KPAD + scol8;
    const int wofs = w << 9;                             // wave's 1KB of chunk

    #define STAGE_A(cn) async_load16(gAt + (size_t)(cn) * 64 * KPAD + (size_t)(t + 1) * 64, \
                                     lds + (nxt << 15) + (cn) * 4096 + wofs)
    #define STAGE_B(cn) async_load16(gBt + (size_t)(cn) * 64 * KPAD + (size_t)(t + 1) * 64, \
                                     lds + (nxt << 15) + 16384 + (cn) * 4096 + wofs)

    // ---- read-side lane addresses (byte offsets, buf0, kk=0)
    const uint32_t L0 = lds_off(lds);
    const uint32_t slot = (uint32_t)((quad ^ (c & 7)) << 4);  // swizzled 16B slot
    const uint32_t aA = (uint32_t)(wr * 128 + c) * 128 + slot;
    const uint32_t aB = 32768u + (uint32_t)(wc * 64 + c) * 128 + slot;

    #define MFMA_HALF(mh) do {                                                   \
        __builtin_amdgcn_s_setprio(1);                                           \
        _Pragma("unroll")                                                        \
        for (int i_ = 0; i_ < 4; i_++) {                                         \
            _Pragma("unroll")                                                    \
            for (int j_ = 0; j_ < 4; j_++)                                       \
                acc[(mh) * 4 + i_][j_] = __builtin_amdgcn_mfma_f32_16x16x32_bf16( \
                    af[i_], bfr[j_], acc[(mh) * 4 + i_][j_], 0, 0, 0);           \
        }                                                                        \
        __builtin_amdgcn_s_setprio(0);                                           \
    } while (0)

    // ---- prologue: stage K-tile 0 into buf 0, full drain once
    {
        #pragma unroll
        for (int cn = 0; cn < 4; cn++)
            async_load16(gAt + (size_t)cn * 64 * KPAD, lds + cn * 4096 + wofs);
        #pragma unroll
        for (int cn = 0; cn < 4; cn++)
            async_load16(gBt + (size_t)cn * 64 * KPAD, lds + 16384 + cn * 4096 + wofs);
        VMW(0);
        BAR;
    }

    // ---- main loop: iter t computes tile t, stages tile t+1
    // issue order B0,B1 | B2,B3 | A0,A2 | A1,A3  ->  waits vmcnt(2) at P1 & P4
    #pragma unroll 1
    for (int t = 0; t < NT; ++t) {
        const int cur = t & 1, nxt = cur ^ 1;
        const bool stg = (t < NT - 1);
        const uint32_t bA = L0 + (uint32_t)(cur << 16) + aA;
        const uint32_t bB = L0 + (uint32_t)(cur << 16) + aB;
        const uint32_t cA = bA ^ 64u, cB = bB ^ 64u;   // kk=1 slot flip
        bf16x8 af[4], bfr[4];

        // P1: kk0, mi 0-3 (A chunks {0,2}, B all)
        af[0] = dsr128(bA);          af[1] = dsr128(bA + 2048);
        af[2] = dsr128(bA + 4096);   af[3] = dsr128(bA + 6144);
        bfr[0] = dsr128(bB);         bfr[1] = dsr128(bB + 2048);
        bfr[2] = dsr128(bB + 4096);  bfr[3] = dsr128(bB + 6144);
        if (stg) { STAGE_B(0); STAGE_B(1); }
        BAR; LGKM0;
        MFMA_HALF(0);
        if (t == NT - 1) { VMW(0); } else { VMW(2); }   // W2: this tile's A1,A3
        BAR;

        // P2: kk0, mi 4-7 (A chunks {1,3}; B regs reused)
        af[0] = dsr128(bA + 8192);   af[1] = dsr128(bA + 10240);
        af[2] = dsr128(bA + 12288);  af[3] = dsr128(bA + 14336);
        if (stg) { STAGE_B(2); STAGE_B(3); }
        BAR; LGKM0;
        MFMA_HALF(1);
        BAR;

        // P3: kk1, mi 0-3
        af[0] = dsr128(cA);          af[1] = dsr128(cA + 2048);
        af[2] = dsr128(cA + 4096);   af[3] = dsr128(cA + 6144);
        bfr[0] = dsr128(cB);         bfr[1] = dsr128(cB + 2048);
        bfr[2] = dsr128(cB + 4096);  bfr[3] = dsr128(cB + 6144);
        if (stg) { STAGE_A(0); STAGE_A(2); }
        BAR; LGKM0;
        MFMA_HALF(0);
        BAR;

        // P4: kk1, mi 4-7
        af[0] = dsr128(cA + 8192);   af[1] = dsr128(cA + 10240);
        af[2] = dsr128(cA + 12288);  af[3] = dsr128(cA + 14336);
        if (stg) { STAGE_A(1); STAGE_A(3); }
        BAR; LGKM0;
        MFMA_HALF(1);
        VMW(2);                                         // W1: next tile minus A1,A3
        BAR;
    }

    // ---- GRU epilogue: lane holds all 4 gates of hidden dim `dim`
    const int dim = (bn * 4 + wc) * 16 + c;
    const float br  = b_ih[dim]       + b_hh[dim];
    const float bz  = b_ih[256 + dim] + b_hh[256 + dim];
    const float bin = b_ih[512 + dim];
    const float bhn = b_hh[512 + dim];

    #pragma unroll
    for (int mi = 0; mi < 8; mi++) {
        const int ubase = bm * 256 + wr * 128 + mi * 16 + quad * 4;
        #pragma unroll
        for (int v = 0; v < 4; v++) {
            int u = ubase + v;
            int node = idx[u];
            if (winner[node] != u) continue;   // only last update writes
            float r  = sigmoidf_(acc[mi][0][v] + br);
            float z  = sigmoidf_(acc[mi][1][v] + bz);
            float nn = tanhf_(acc[mi][2][v] + bin + r * (acc[mi][3][v] + bhn));
            float h  = mem[(size_t)node * NODE_DIM + dim];
            out[(size_t)node * NODE_DIM + dim] = (1.f - z) * nn + z * h;
        }
    }
    #undef STAGE_A
    #undef STAGE_B
    #undef MFMA_HALF
}

extern "C" void kernel_launch(void* const* d_in, const int* in_sizes, int n_in,
                              void* d_out, int out_size, void* d_ws, size_t ws_size,
                              hipStream_t stream) {
    const float* memory   = (const float*)d_in[0];
    const float* messages = (const float*)d_in[1];
    const int*   node_idx = (const int*)d_in[2];
    const float* W_ih     = (const float*)d_in[3];
    const float* W_hh     = (const float*)d_in[4];
    const float* b_ih     = (const float*)d_in[5];
    const float* b_hh     = (const float*)d_in[6];
    float* out = (float*)d_out;

    char* ws = (char*)d_ws;
    bf16* X  = (bf16*)ws;                                           // 120 MiB
    bf16* Wc = (bf16*)(ws + (size_t)NUM_UPD * KPAD * 2);            // 1.9 MiB
    int* winner = (int*)(ws + (size_t)NUM_UPD * KPAD * 2 + (size_t)NOUT * KPAD * 2);

    hipMemsetAsync(winner, 0xFF, NUM_NODES * sizeof(int), stream);  // all -1
    k_winner <<<NUM_UPD / 256, 256, 0, stream>>>(node_idx, winner);
    k_copy   <<<2048, 256, 0, stream>>>(memory, winner, out);
    k_prep_wc<<<NOUT, 256, 0, stream>>>(W_ih, W_hh, Wc);
    k_prep_x <<<NUM_UPD, 448, 0, stream>>>(messages, memory, node_idx, X);
    k_gemm   <<<(NUM_UPD / 256) * (NOUT / 256), 512, 0, stream>>>(
        X, Wc, memory, node_idx, winner, b_ih, b_hh, out);
}